// Round 3
// baseline (549.496 us; speedup 1.0000x reference)
//
#include <hip/hip_runtime.h>
#include <hip/hip_bf16.h>
#include <cstdint>

typedef __attribute__((ext_vector_type(8))) short short8;
typedef __attribute__((ext_vector_type(4))) short short4v;
typedef __attribute__((ext_vector_type(4))) float floatx4;

constexpr int B_ = 2, L_ = 4096, D_ = 1024, H_ = 16, DH = 64, F_ = 4096;
constexpr int M_ = B_ * L_;        // 8192 rows
constexpr int NQKV = 3 * D_;       // 3072
constexpr int VT_GUARD = 512;

// ---------------- workspace layout (bytes) ----------------
constexpr size_t OFF_XB  = 0;                                       // bf16 [M][D]
constexpr size_t OFF_WCT = OFF_XB  + (size_t)M_ * D_ * 2;           // bf16 [3072][1024]
constexpr size_t OFF_W1T = OFF_WCT + (size_t)NQKV * D_ * 2;         // bf16 [4096][1024]
constexpr size_t OFF_W2T = OFF_W1T + (size_t)F_ * D_ * 2;           // bf16 [1024][4096]
constexpr size_t OFF_QKV = OFF_W2T + (size_t)D_ * F_ * 2;           // bf16 [M][3072]
constexpr size_t OFF_VT  = OFF_QKV + (size_t)M_ * NQKV * 2;
constexpr size_t OFF_ATT = OFF_VT  + ((size_t)B_*H_*DH*L_ + 2*VT_GUARD) * 2;
constexpr size_t OFF_HB  = OFF_ATT + (size_t)M_ * D_ * 2;
constexpr size_t OFF_MID = OFF_HB  + (size_t)M_ * D_ * 2;           // bf16 [M][F]

static __device__ __forceinline__ float b2f(unsigned short u) {
    union { unsigned int i; float f; } v; v.i = ((unsigned int)u) << 16; return v.f;
}

static __device__ __forceinline__ void gload16(const void* g, void* l) {
    __builtin_amdgcn_global_load_lds(
        (const __attribute__((address_space(1))) uint32_t*)g,
        (__attribute__((address_space(3))) uint32_t*)l, 16, 0, 0);
}

// ---------------- f32 -> bf16 convert (x) ----------------
__global__ __launch_bounds__(256) void k_cvt_x(const float* __restrict__ x,
                                               __hip_bfloat16* __restrict__ xb) {
    int i = (blockIdx.x * 256 + threadIdx.x) * 8;
    float4 a = *(const float4*)(x + i);
    float4 b = *(const float4*)(x + i + 4);
    alignas(16) __hip_bfloat16 t[8];
    t[0] = __float2bfloat16(a.x); t[1] = __float2bfloat16(a.y);
    t[2] = __float2bfloat16(a.z); t[3] = __float2bfloat16(a.w);
    t[4] = __float2bfloat16(b.x); t[5] = __float2bfloat16(b.y);
    t[6] = __float2bfloat16(b.z); t[7] = __float2bfloat16(b.w);
    *(uint4*)(xb + i) = *(const uint4*)t;
}

// ---------------- transpose+convert: in [R][C] f32 -> out [C][R] bf16 ----------------
__global__ __launch_bounds__(256) void k_tcvt(const float* __restrict__ in,
                                              __hip_bfloat16* __restrict__ out,
                                              int R, int C) {
    __shared__ float t[64][65];
    int tx = threadIdx.x & 63, ty4 = threadIdx.x >> 6;
    int c0 = blockIdx.x * 64, r0 = blockIdx.y * 64;
#pragma unroll
    for (int i = 0; i < 16; i++) {
        int r = ty4 + i * 4;
        t[r][tx] = in[(size_t)(r0 + r) * C + c0 + tx];
    }
    __syncthreads();
#pragma unroll
    for (int i = 0; i < 16; i++) {
        int r = ty4 + i * 4;
        out[(size_t)(c0 + r) * R + r0 + tx] = __float2bfloat16(t[tx][r]);
    }
}

// ---------------- V transpose ----------------
__global__ __launch_bounds__(256) void k_vtrans(const __hip_bfloat16* __restrict__ qkv,
                                                __hip_bfloat16* __restrict__ vtg) {
    __shared__ __hip_bfloat16 t[64][72];
    int tx = threadIdx.x & 63, ty4 = threadIdx.x >> 6;
    int bh = blockIdx.y, b = bh >> 4, h = bh & 15;
    int j0 = blockIdx.x * 64;
#pragma unroll
    for (int i = 0; i < 16; i++) {
        int j = ty4 + i * 4;
        t[j][tx] = qkv[(size_t)(b * L_ + j0 + j) * NQKV + 2 * D_ + h * DH + tx];
    }
    __syncthreads();
#pragma unroll
    for (int i = 0; i < 16; i++) {
        int d = ty4 + i * 4;
        vtg[(long)(bh * DH + d) * L_ + j0 + tx] = t[tx][d];
    }
}

// ---------------- 128x128 prefetch-double-buffered GEMM ----------------
// C[8192][NBN*128] = A[8192][KTOT] * BT[NBN*128][KTOT]^T
// 4 waves (2m x 2n), per-wave 64x64 output. LDS 64KB -> 2 blocks/CU.
// Per K-tile: stage(t+1) at top (8 gload_lds), compute (no internal barriers),
// then vmcnt(0) + s_barrier once. Swizzled LDS (verified 0-conflict pattern).
template<int NBN, int GM, int EPI, int KTOT>
__global__ __launch_bounds__(256, 2)
void k_g2(const __hip_bfloat16* __restrict__ A, const __hip_bfloat16* __restrict__ BT,
          const float* __restrict__ b0p, const float* __restrict__ b1p,
          const float* __restrict__ b2p,
          __hip_bfloat16* __restrict__ obf, float* __restrict__ of32,
          const __hip_bfloat16* __restrict__ hres) {
    constexpr int KT = KTOT / 64;
    constexpr int NTOT = NBN * 128;
    constexpr int PER = GM * NBN;
    // LDS: [buf][kh][128 rows][32 elem]
    __shared__ __hip_bfloat16 As[2 * 2 * 128 * 32];
    __shared__ __hip_bfloat16 Bs[2 * 2 * 128 * 32];

    const int tid = threadIdx.x, wave = tid >> 6, lane = tid & 63;
    const int lo = lane & 15, hi = lane >> 4;
    const int wm = wave >> 1, wn = wave & 1;

    // group-major decode + contiguous XCD chunks
    const int nwg = gridDim.x, q = nwg >> 3;
    const int bid = blockIdx.x;
    const int swz = (bid & 7) * q + (bid >> 3);
    const int g = swz / PER, r = swz % PER;
    const int bm = g * GM + (r % GM);
    const int bn = r / GM;
    const size_t m0 = (size_t)bm * 128, n0 = (size_t)bn * 128;

    // staging: per thread, row = s*64 + (tid>>2), 16B chunk = (tid&3)^((tid>>3)&3)
    const int chunkT = ((tid & 3) ^ ((tid >> 3) & 3)) * 8;
    const __hip_bfloat16* aG = A  + (m0 + (tid >> 2)) * (size_t)KTOT + chunkT;
    const __hip_bfloat16* bG = BT + (n0 + (tid >> 2)) * (size_t)KTOT + chunkT;
    const int ldsOff = wave * 512;          // per (s): s*2048 + wave*512 (+lane*8 by HW)

    // fragment read offsets: row*32 + swizzled slot
    const int swz16 = (hi ^ ((lo >> 1) & 3)) * 8;
    const int aOff = (wm * 64 + lo) * 32 + swz16;
    const int bOff = (wn * 64 + lo) * 32 + swz16;

    floatx4 acc[4][4] = {};

#define STAGE(buf, t)                                                         \
    _Pragma("unroll")                                                         \
    for (int kh = 0; kh < 2; ++kh)                                            \
        _Pragma("unroll")                                                     \
        for (int s = 0; s < 2; ++s) {                                         \
            gload16(aG + (size_t)(t) * 64 + kh * 32 + (size_t)s * 64 * KTOT,  \
                    As + (buf * 2 + kh) * 4096 + s * 2048 + ldsOff);          \
            gload16(bG + (size_t)(t) * 64 + kh * 32 + (size_t)s * 64 * KTOT,  \
                    Bs + (buf * 2 + kh) * 4096 + s * 2048 + ldsOff);          \
        }

    // prologue: stage tile 0 into buf 0, drain, barrier
    STAGE(0, 0)
    asm volatile("s_waitcnt vmcnt(0)" ::: "memory");
    __builtin_amdgcn_s_barrier();

    for (int t = 0; t < KT; ++t) {
        const int cur = t & 1;
        if (t + 1 < KT) {
            const int nxt = cur ^ 1;
            STAGE(nxt, t + 1)
        }
        const __hip_bfloat16* aU0 = As + (cur * 2 + 0) * 4096;
        const __hip_bfloat16* bU0 = Bs + (cur * 2 + 0) * 4096;
        const __hip_bfloat16* aU1 = As + (cur * 2 + 1) * 4096;
        const __hip_bfloat16* bU1 = Bs + (cur * 2 + 1) * 4096;
#pragma unroll
        for (int kh = 0; kh < 2; ++kh) {
            const __hip_bfloat16* aU = kh ? aU1 : aU0;
            const __hip_bfloat16* bU = kh ? bU1 : bU0;
            short8 afr[4], bfr[4];
#pragma unroll
            for (int i = 0; i < 4; ++i) {
                afr[i] = *(const short8*)(aU + aOff + i * 512);
                bfr[i] = *(const short8*)(bU + bOff + i * 512);
            }
#pragma unroll
            for (int mf = 0; mf < 4; ++mf)
#pragma unroll
                for (int nf = 0; nf < 4; ++nf)
                    acc[mf][nf] = __builtin_amdgcn_mfma_f32_16x16x32_bf16(
                        afr[mf], bfr[nf], acc[mf][nf], 0, 0, 0);
        }
        asm volatile("s_waitcnt vmcnt(0)" ::: "memory");
        __builtin_amdgcn_sched_barrier(0);
        __builtin_amdgcn_s_barrier();
    }
#undef STAGE

    // ---- epilogue ----
#pragma unroll
    for (int mf = 0; mf < 4; ++mf) {
        const int row = (int)m0 + wm * 64 + mf * 16 + hi * 4;
#pragma unroll
        for (int nf = 0; nf < 4; ++nf) {
            const int col = (int)n0 + wn * 64 + nf * 16 + lo;
#pragma unroll
            for (int rr = 0; rr < 4; ++rr) {
                float v = acc[mf][nf][rr];
                const size_t ro = (size_t)(row + rr);
                if (EPI == 0) {
                    float bia = (col < 1024) ? b0p[col]
                              : (col < 2048 ? b1p[col - 1024] : b2p[col - 2048]);
                    obf[ro * NQKV + col] = __float2bfloat16(v + bia);
                } else if (EPI == 1) {
                    v += b0p[col];
                    v = 0.5f * v * (1.0f + erff(v * 0.70710678118654752440f));
                    obf[ro * F_ + col] = __float2bfloat16(v);
                } else {
                    v += b0p[col];
                    v += b2f(*(const unsigned short*)&hres[ro * D_ + col]);
                    of32[ro * D_ + col] = v;
                }
            }
        }
    }
    (void)NTOT;
}

// ---------------- sliding-window attention (unchanged, verified) ----------------
__global__ __launch_bounds__(256, 2)
void k_attn(const __hip_bfloat16* __restrict__ qkv, const float* __restrict__ mask,
            const __hip_bfloat16* __restrict__ vtg, __hip_bfloat16* __restrict__ attnb) {
    constexpr int PS = 296;
    __shared__ __hip_bfloat16 P[4][16 * PS];
    const int tid = threadIdx.x, wave = tid >> 6, lane = tid & 63;
    const int bh = blockIdx.y, b = bh >> 4, h = bh & 15;
    const int q0 = blockIdx.x * 64 + wave * 16;
    const int lo = lane & 15, hi = lane >> 4;

    short8 qf0, qf1;
    {
        const __hip_bfloat16* qb = qkv + (size_t)(b * L_ + q0 + lo) * NQKV + h * DH + hi * 8;
        qf0 = *(const short8*)qb;
        qf1 = *(const short8*)(qb + 32);
    }

    floatx4 sc[17];
    const __hip_bfloat16* kcol = qkv + (size_t)b * L_ * NQKV + D_ + h * DH + hi * 8;
#pragma unroll
    for (int t = 0; t < 17; t++) {
        int jg = q0 - 128 + t * 16 + lo;
        int jc = jg < 0 ? 0 : (jg >= L_ ? L_ - 1 : jg);
        const __hip_bfloat16* kb = kcol + (size_t)jc * NQKV;
        short8 kf0 = *(const short8*)kb;
        short8 kf1 = *(const short8*)(kb + 32);
        floatx4 a = {};
        a = __builtin_amdgcn_mfma_f32_16x16x32_bf16(qf0, kf0, a, 0, 0, 0);
        a = __builtin_amdgcn_mfma_f32_16x16x32_bf16(qf1, kf1, a, 0, 0, 0);
        float mval = mask[b * L_ + jc];
        bool jok = (jg >= 0) && (jg < L_) && (mval == 0.0f);
#pragma unroll
        for (int r = 0; r < 4; r++) {
            int qi = q0 + hi * 4 + r;
            bool ok = jok && (jg >= qi - 128) && (jg <= qi + 128);
            a[r] = ok ? a[r] * 0.125f : -1e9f;
        }
        sc[t] = a;
    }

#pragma unroll
    for (int r = 0; r < 4; r++) {
        float m = -3e38f;
#pragma unroll
        for (int t = 0; t < 17; t++) m = fmaxf(m, sc[t][r]);
        m = fmaxf(m, __shfl_xor(m, 1));
        m = fmaxf(m, __shfl_xor(m, 2));
        m = fmaxf(m, __shfl_xor(m, 4));
        m = fmaxf(m, __shfl_xor(m, 8));
        float s = 0.0f;
#pragma unroll
        for (int t = 0; t < 17; t++) { float e = __expf(sc[t][r] - m); sc[t][r] = e; s += e; }
        s += __shfl_xor(s, 1); s += __shfl_xor(s, 2);
        s += __shfl_xor(s, 4); s += __shfl_xor(s, 8);
        float inv = 1.0f / s;
#pragma unroll
        for (int t = 0; t < 17; t++) sc[t][r] *= inv;
    }

    __hip_bfloat16* Pw = &P[wave][0];
#pragma unroll
    for (int t = 0; t < 17; t++)
#pragma unroll
        for (int r = 0; r < 4; r++)
            Pw[(hi * 4 + r) * PS + t * 16 + lo] = __float2bfloat16(sc[t][r]);
    {
        int zr = lane >> 2, zc = 272 + (lane & 3) * 4;
        __hip_bfloat16 z = __float2bfloat16(0.0f);
#pragma unroll
        for (int i = 0; i < 4; i++) Pw[zr * PS + zc + i] = z;
    }

    floatx4 o[4] = {};
#pragma unroll
    for (int st = 0; st < 9; st++) {
        short8 pa = *(const short8*)(Pw + lo * PS + st * 32 + hi * 8);
        int jb = q0 - 128 + st * 32 + hi * 8;
#pragma unroll
        for (int dt = 0; dt < 4; dt++) {
            const __hip_bfloat16* vb = vtg + (long)(bh * DH + dt * 16 + lo) * L_ + jb;
            short8 vf = *(const short8*)vb;
            o[dt] = __builtin_amdgcn_mfma_f32_16x16x32_bf16(pa, vf, o[dt], 0, 0, 0);
        }
    }

#pragma unroll
    for (int dt = 0; dt < 4; dt++)
#pragma unroll
        for (int r = 0; r < 4; r++) {
            int row = q0 + hi * 4 + r;
            attnb[(size_t)(b * L_ + row) * D_ + h * DH + dt * 16 + lo] =
                __float2bfloat16(o[dt][r]);
        }
}

// ---------------- residual + LayerNorm ----------------
__global__ __launch_bounds__(256)
void k_ln(const float* __restrict__ x, const __hip_bfloat16* __restrict__ attnb,
          const float* __restrict__ g, const float* __restrict__ bt,
          __hip_bfloat16* __restrict__ hb) {
    const int row = blockIdx.x, tid = threadIdx.x;
    const int c4 = tid * 4;
    float4 xv = *(const float4*)(x + (size_t)row * D_ + c4);
    short4v av = *(const short4v*)(attnb + (size_t)row * D_ + c4);
    float h0 = xv.x + b2f((unsigned short)av[0]);
    float h1 = xv.y + b2f((unsigned short)av[1]);
    float h2 = xv.z + b2f((unsigned short)av[2]);
    float h3 = xv.w + b2f((unsigned short)av[3]);
    float s = h0 + h1 + h2 + h3;
    float q = h0 * h0 + h1 * h1 + h2 * h2 + h3 * h3;
#pragma unroll
    for (int off = 32; off > 0; off >>= 1) {
        s += __shfl_down(s, off);
        q += __shfl_down(q, off);
    }
    __shared__ float red[8];
    int wave = tid >> 6, lane = tid & 63;
    if (lane == 0) { red[wave] = s; red[4 + wave] = q; }
    __syncthreads();
    s = red[0] + red[1] + red[2] + red[3];
    q = red[4] + red[5] + red[6] + red[7];
    float mu = s * (1.0f / D_);
    float var = q * (1.0f / D_) - mu * mu;
    float inv = rsqrtf(var + 1e-5f);
    float4 gv = *(const float4*)(g + c4);
    float4 bv = *(const float4*)(bt + c4);
    alignas(8) __hip_bfloat16 ov[4];
    ov[0] = __float2bfloat16((h0 - mu) * inv * gv.x + bv.x);
    ov[1] = __float2bfloat16((h1 - mu) * inv * gv.y + bv.y);
    ov[2] = __float2bfloat16((h2 - mu) * inv * gv.z + bv.z);
    ov[3] = __float2bfloat16((h3 - mu) * inv * gv.w + bv.w);
    *(short4v*)(hb + (size_t)row * D_ + c4) = *(const short4v*)ov;
}

// ---------------- launch ----------------
extern "C" void kernel_launch(void* const* d_in, const int* in_sizes, int n_in,
                              void* d_out, int out_size, void* d_ws, size_t ws_size,
                              hipStream_t stream) {
    const float* x    = (const float*)d_in[0];
    const float* mask = (const float*)d_in[1];
    const float* Wq   = (const float*)d_in[2];
    const float* bq   = (const float*)d_in[3];
    const float* Wk   = (const float*)d_in[4];
    const float* bk   = (const float*)d_in[5];
    const float* Wv   = (const float*)d_in[6];
    const float* bv   = (const float*)d_in[7];
    const float* ln_g = (const float*)d_in[8];
    const float* ln_b = (const float*)d_in[9];
    const float* W1   = (const float*)d_in[10];
    const float* b1   = (const float*)d_in[11];
    const float* W2   = (const float*)d_in[12];
    const float* b2   = (const float*)d_in[13];
    float* out = (float*)d_out;
    char* ws = (char*)d_ws;

    __hip_bfloat16* xb   = (__hip_bfloat16*)(ws + OFF_XB);
    __hip_bfloat16* wct  = (__hip_bfloat16*)(ws + OFF_WCT);
    __hip_bfloat16* w1t  = (__hip_bfloat16*)(ws + OFF_W1T);
    __hip_bfloat16* w2t  = (__hip_bfloat16*)(ws + OFF_W2T);
    __hip_bfloat16* qkvb = (__hip_bfloat16*)(ws + OFF_QKV);
    __hip_bfloat16* vtg  = (__hip_bfloat16*)(ws + OFF_VT) + VT_GUARD;
    __hip_bfloat16* attb = (__hip_bfloat16*)(ws + OFF_ATT);
    __hip_bfloat16* hb   = (__hip_bfloat16*)(ws + OFF_HB);
    __hip_bfloat16* midb = (__hip_bfloat16*)(ws + OFF_MID);

    // input conversions
    k_cvt_x<<<(M_ * D_) / 2048, 256, 0, stream>>>(x, xb);
    k_tcvt<<<dim3(D_ / 64, D_ / 64), 256, 0, stream>>>(Wq, wct,                   D_, D_);
    k_tcvt<<<dim3(D_ / 64, D_ / 64), 256, 0, stream>>>(Wk, wct + 1024 * 1024,     D_, D_);
    k_tcvt<<<dim3(D_ / 64, D_ / 64), 256, 0, stream>>>(Wv, wct + 2 * 1024 * 1024, D_, D_);
    k_tcvt<<<dim3(F_ / 64, D_ / 64), 256, 0, stream>>>(W1, w1t, D_, F_);
    k_tcvt<<<dim3(D_ / 64, F_ / 64), 256, 0, stream>>>(W2, w2t, F_, D_);

    // fused QKV projection: grid 64*24 = 1536
    k_g2<24, 8, 0, D_><<<64 * 24, 256, 0, stream>>>(
        xb, wct, bq, bk, bv, qkvb, nullptr, nullptr);

    // V transpose, attention
    k_vtrans<<<dim3(L_ / 64, B_ * H_), 256, 0, stream>>>(qkvb, vtg);
    k_attn<<<dim3(L_ / 64, B_ * H_), 256, 0, stream>>>(qkvb, mask, vtg, attb);

    // residual + LN
    k_ln<<<M_, 256, 0, stream>>>(x, attb, ln_g, ln_b, hb);

    // MLP: grid 64*32 = 2048 ; grid 64*8 = 512
    k_g2<32, 8, 1, D_><<<64 * 32, 256, 0, stream>>>(
        hb, w1t, b1, nullptr, nullptr, midb, nullptr, nullptr);
    k_g2<8, 2, 2, F_><<<64 * 8, 256, 0, stream>>>(
        midb, w2t, b2, nullptr, nullptr, nullptr, out, hb);
}

// Round 5
// 505.419 us; speedup vs baseline: 1.0872x; 1.0872x over previous
//
#include <hip/hip_runtime.h>
#include <hip/hip_bf16.h>
#include <cstdint>

typedef __attribute__((ext_vector_type(8))) short short8;
typedef __attribute__((ext_vector_type(4))) short short4v;
typedef __attribute__((ext_vector_type(4))) float floatx4;

constexpr int B_ = 2, L_ = 4096, D_ = 1024, H_ = 16, DH = 64, F_ = 4096;
constexpr int M_ = B_ * L_;        // 8192 rows
constexpr int NQKV = 3 * D_;       // 3072
constexpr int VT_GUARD = 512;

// ---------------- workspace layout (bytes) ----------------
constexpr size_t OFF_XB  = 0;                                       // bf16 [M][D]
constexpr size_t OFF_WCT = OFF_XB  + (size_t)M_ * D_ * 2;           // bf16 [3072][1024]
constexpr size_t OFF_W1T = OFF_WCT + (size_t)NQKV * D_ * 2;         // bf16 [4096][1024]
constexpr size_t OFF_W2T = OFF_W1T + (size_t)F_ * D_ * 2;           // bf16 [1024][4096]
constexpr size_t OFF_QKV = OFF_W2T + (size_t)D_ * F_ * 2;           // bf16 [M][3072]
constexpr size_t OFF_VT  = OFF_QKV + (size_t)M_ * NQKV * 2;
constexpr size_t OFF_ATT = OFF_VT  + ((size_t)B_*H_*DH*L_ + 2*VT_GUARD) * 2;
constexpr size_t OFF_HB  = OFF_ATT + (size_t)M_ * D_ * 2;
constexpr size_t OFF_MID = OFF_HB  + (size_t)M_ * D_ * 2;           // bf16 [M][F]

static __device__ __forceinline__ float b2f(unsigned short u) {
    union { unsigned int i; float f; } v; v.i = ((unsigned int)u) << 16; return v.f;
}

static __device__ __forceinline__ void gload16(const void* g, void* l) {
    __builtin_amdgcn_global_load_lds(
        (const __attribute__((address_space(1))) uint32_t*)g,
        (__attribute__((address_space(3))) uint32_t*)l, 16, 0, 0);
}

// ---------------- f32 -> bf16 convert (x) ----------------
__global__ __launch_bounds__(256) void k_cvt_x(const float* __restrict__ x,
                                               __hip_bfloat16* __restrict__ xb) {
    int i = (blockIdx.x * 256 + threadIdx.x) * 8;
    float4 a = *(const float4*)(x + i);
    float4 b = *(const float4*)(x + i + 4);
    alignas(16) __hip_bfloat16 t[8];
    t[0] = __float2bfloat16(a.x); t[1] = __float2bfloat16(a.y);
    t[2] = __float2bfloat16(a.z); t[3] = __float2bfloat16(a.w);
    t[4] = __float2bfloat16(b.x); t[5] = __float2bfloat16(b.y);
    t[6] = __float2bfloat16(b.z); t[7] = __float2bfloat16(b.w);
    *(uint4*)(xb + i) = *(const uint4*)t;
}

// ---------------- transpose+convert: in [R][C] f32 -> out [C][R] bf16 ----------------
__global__ __launch_bounds__(256) void k_tcvt(const float* __restrict__ in,
                                              __hip_bfloat16* __restrict__ out,
                                              int R, int C) {
    __shared__ float t[64][65];
    int tx = threadIdx.x & 63, ty4 = threadIdx.x >> 6;
    int c0 = blockIdx.x * 64, r0 = blockIdx.y * 64;
#pragma unroll
    for (int i = 0; i < 16; i++) {
        int r = ty4 + i * 4;
        t[r][tx] = in[(size_t)(r0 + r) * C + c0 + tx];
    }
    __syncthreads();
#pragma unroll
    for (int i = 0; i < 16; i++) {
        int r = ty4 + i * 4;
        out[(size_t)(c0 + r) * R + r0 + tx] = __float2bfloat16(t[tx][r]);
    }
}

// ---------------- V transpose ----------------
__global__ __launch_bounds__(256) void k_vtrans(const __hip_bfloat16* __restrict__ qkv,
                                                __hip_bfloat16* __restrict__ vtg) {
    __shared__ __hip_bfloat16 t[64][72];
    int tx = threadIdx.x & 63, ty4 = threadIdx.x >> 6;
    int bh = blockIdx.y, b = bh >> 4, h = bh & 15;
    int j0 = blockIdx.x * 64;
#pragma unroll
    for (int i = 0; i < 16; i++) {
        int j = ty4 + i * 4;
        t[j][tx] = qkv[(size_t)(b * L_ + j0 + j) * NQKV + 2 * D_ + h * DH + tx];
    }
    __syncthreads();
#pragma unroll
    for (int i = 0; i < 16; i++) {
        int d = ty4 + i * 4;
        vtg[(long)(bh * DH + d) * L_ + j0 + tx] = t[tx][d];
    }
}

// ---------------- 256xBN 8-wave phase-template GEMM (m201/m248 port) ----------------
// C[8192][NBN*BN] = A[8192][KTOT] * BT[NBN*BN][KTOT]^T,  BN = NFRAG*64.
// 512 thr = 8 waves (2m x 4n); per-wave 128 x NFRAG*16 output.
// Per K-tile: 4 phases, each {ds_read subtile, stage 2 gload_lds, [counted vmcnt],
// barrier, setprio+MFMA, barrier}. vmcnt(4)@ph1, vmcnt(2)@ph3 - never 0 in loop.
// LDS rows 128B with 8-chunk XOR swizzle (inverse-swizzled global source).
template<int NFRAG, int GM, int EPI, int KTOT, int NBN>
__global__ __launch_bounds__(512, 2)
void k_g8(const __hip_bfloat16* __restrict__ A, const __hip_bfloat16* __restrict__ BT,
          const float* __restrict__ b0p, const float* __restrict__ b1p,
          const float* __restrict__ b2p,
          __hip_bfloat16* __restrict__ obf, float* __restrict__ of32,
          const __hip_bfloat16* __restrict__ hres) {
    constexpr int BN = NFRAG * 64;
    constexpr int KT = KTOT / 64;
    constexpr int PER = GM * NBN;

    __shared__ __hip_bfloat16 AS[2][4 * 4096];
    __shared__ __hip_bfloat16 BS[2][NFRAG * 4096];

    const int tid = threadIdx.x, wave = tid >> 6, lane = tid & 63;
    const int lo = lane & 15, hi = lane >> 4;
    const int wm = wave >> 2, wn = wave & 3;

    // bijective XCD swizzle + group-major (GM bm-rows per group)
    const int nwg = gridDim.x, q = nwg >> 3;
    const int bid = blockIdx.x;
    const int swz = (bid & 7) * q + (bid >> 3);
    const int g = swz / PER, r = swz % PER;
    const int bm = g * GM + (r % GM);
    const int bn = r / GM;
    const size_t m0 = (size_t)bm * 256, n0 = (size_t)bn * BN;

    // staging: thread covers row srow (within 64-row sweep); global chunk pre-swizzled
    const int srow = tid >> 3;
    const int gcc = (tid & 7) ^ (srow & 7);
    const __hip_bfloat16* aG = A  + (m0 + srow) * (size_t)KTOT + gcc * 8;
    const __hip_bfloat16* bG = BT + (n0 + srow) * (size_t)KTOT + gcc * 8;
    const int ldst = wave * 512;    // element offset inside sweep region (+lane*8 by HW)

    // fragment read: addr(elem) = R*64 + ((k*4+hi)^(R&7))*8 ; R&7 == lo&7
    int ccr[2];
#pragma unroll
    for (int k = 0; k < 2; ++k) ccr[k] = ((k * 4 + hi) ^ (lo & 7)) * 8;
    const int Ra = wm * 128 + lo;       // A base row for this thread
    const int Rb0 = wn * (NFRAG * 16) + lo;

    floatx4 acc[8][NFRAG] = {};

#define STG_A(buf, sw, tn) gload16(aG + (size_t)(sw) * 64 * KTOT + (size_t)(tn) * 64, \
                                   &AS[buf][(sw) * 4096 + ldst])
#define STG_B(buf, sw, tn) gload16(bG + (size_t)(sw) * 64 * KTOT + (size_t)(tn) * 64, \
                                   &BS[buf][(sw) * 4096 + ldst])

    // prologue: stage tile 0 (phase order), drain once, barrier
    STG_B(0, 0, 0); STG_B(0, 1, 0);
    if (NFRAG == 4) { STG_B(0, 2, 0); STG_B(0, 3, 0); }
    STG_A(0, 0, 0); STG_A(0, 2, 0); STG_A(0, 1, 0); STG_A(0, 3, 0);
    asm volatile("s_waitcnt vmcnt(0)" ::: "memory");
    __builtin_amdgcn_s_barrier();

    for (int t = 0; t < KT; ++t) {
        const int cur = t & 1, nxt = cur ^ 1;
        const int tn = (t + 1 < KT) ? (t + 1) : 0;
        const __hip_bfloat16* aL = &AS[cur][0];
        const __hip_bfloat16* bL = &BS[cur][0];
        short8 bfr[NFRAG][2], afr[2][2];

        // ================= phase 0 =================
#pragma unroll
        for (int gf = 0; gf < NFRAG; ++gf)
#pragma unroll
            for (int k = 0; k < 2; ++k)
                bfr[gf][k] = *(const short8*)(bL + (Rb0 + gf * 16) * 64 + ccr[k]);
#pragma unroll
        for (int f = 0; f < 2; ++f)
#pragma unroll
            for (int k = 0; k < 2; ++k)
                afr[f][k] = *(const short8*)(aL + (Ra + f * 16) * 64 + ccr[k]);
        STG_B(nxt, 0, tn); STG_B(nxt, 1, tn);
        __builtin_amdgcn_s_barrier();
        __builtin_amdgcn_s_setprio(1);
#pragma unroll
        for (int f = 0; f < 2; ++f)
#pragma unroll
            for (int gf = 0; gf < NFRAG; ++gf)
#pragma unroll
                for (int k = 0; k < 2; ++k)
                    acc[f][gf] = __builtin_amdgcn_mfma_f32_16x16x32_bf16(
                        afr[f][k], bfr[gf][k], acc[f][gf], 0, 0, 0);
        __builtin_amdgcn_s_setprio(0);
        __builtin_amdgcn_s_barrier();

        // ================= phase 1 =================
#pragma unroll
        for (int f = 0; f < 2; ++f)
#pragma unroll
            for (int k = 0; k < 2; ++k)
                afr[f][k] = *(const short8*)(aL + (Ra + (2 + f) * 16) * 64 + ccr[k]);
        if (NFRAG == 4) { STG_B(nxt, 2, tn); STG_B(nxt, 3, tn); }
        else            { STG_A(nxt, 0, tn); STG_A(nxt, 2, tn); }
        asm volatile("s_waitcnt vmcnt(4)" ::: "memory");
        __builtin_amdgcn_s_barrier();
        __builtin_amdgcn_s_setprio(1);
#pragma unroll
        for (int f = 0; f < 2; ++f)
#pragma unroll
            for (int gf = 0; gf < NFRAG; ++gf)
#pragma unroll
                for (int k = 0; k < 2; ++k)
                    acc[2 + f][gf] = __builtin_amdgcn_mfma_f32_16x16x32_bf16(
                        afr[f][k], bfr[gf][k], acc[2 + f][gf], 0, 0, 0);
        __builtin_amdgcn_s_setprio(0);
        __builtin_amdgcn_s_barrier();

        // ================= phase 2 =================
#pragma unroll
        for (int f = 0; f < 2; ++f)
#pragma unroll
            for (int k = 0; k < 2; ++k)
                afr[f][k] = *(const short8*)(aL + (Ra + (4 + f) * 16) * 64 + ccr[k]);
        if (NFRAG == 4) { STG_A(nxt, 0, tn); STG_A(nxt, 2, tn); }
        else            { STG_A(nxt, 1, tn); STG_A(nxt, 3, tn); }
        __builtin_amdgcn_s_barrier();
        __builtin_amdgcn_s_setprio(1);
#pragma unroll
        for (int f = 0; f < 2; ++f)
#pragma unroll
            for (int gf = 0; gf < NFRAG; ++gf)
#pragma unroll
                for (int k = 0; k < 2; ++k)
                    acc[4 + f][gf] = __builtin_amdgcn_mfma_f32_16x16x32_bf16(
                        afr[f][k], bfr[gf][k], acc[4 + f][gf], 0, 0, 0);
        __builtin_amdgcn_s_setprio(0);
        __builtin_amdgcn_s_barrier();

        // ================= phase 3 =================
#pragma unroll
        for (int f = 0; f < 2; ++f)
#pragma unroll
            for (int k = 0; k < 2; ++k)
                afr[f][k] = *(const short8*)(aL + (Ra + (6 + f) * 16) * 64 + ccr[k]);
        if (NFRAG == 4) { STG_A(nxt, 1, tn); STG_A(nxt, 3, tn); }
        asm volatile("s_waitcnt vmcnt(2)" ::: "memory");
        __builtin_amdgcn_s_barrier();
        __builtin_amdgcn_s_setprio(1);
#pragma unroll
        for (int f = 0; f < 2; ++f)
#pragma unroll
            for (int gf = 0; gf < NFRAG; ++gf)
#pragma unroll
                for (int k = 0; k < 2; ++k)
                    acc[6 + f][gf] = __builtin_amdgcn_mfma_f32_16x16x32_bf16(
                        afr[f][k], bfr[gf][k], acc[6 + f][gf], 0, 0, 0);
        __builtin_amdgcn_s_setprio(0);
        __builtin_amdgcn_s_barrier();
    }
#undef STG_A
#undef STG_B

    // ---- epilogue ----
#pragma unroll
    for (int mf = 0; mf < 8; ++mf) {
        const int row = (int)m0 + wm * 128 + mf * 16 + hi * 4;
#pragma unroll
        for (int gf = 0; gf < NFRAG; ++gf) {
            const int col = (int)n0 + wn * (NFRAG * 16) + gf * 16 + lo;
#pragma unroll
            for (int rr = 0; rr < 4; ++rr) {
                float v = acc[mf][gf][rr];
                const size_t ro = (size_t)(row + rr);
                if (EPI == 0) {
                    float bia = (col < 1024) ? b0p[col]
                              : (col < 2048 ? b1p[col - 1024] : b2p[col - 2048]);
                    obf[ro * NQKV + col] = __float2bfloat16(v + bia);
                } else if (EPI == 1) {
                    v += b0p[col];
                    v = 0.5f * v * (1.0f + erff(v * 0.70710678118654752440f));
                    obf[ro * F_ + col] = __float2bfloat16(v);
                } else {
                    v += b0p[col];
                    v += b2f(*(const unsigned short*)&hres[ro * D_ + col]);
                    of32[ro * D_ + col] = v;
                }
            }
        }
    }
}

// ---------------- sliding-window attention (unchanged, verified) ----------------
__global__ __launch_bounds__(256, 2)
void k_attn(const __hip_bfloat16* __restrict__ qkv, const float* __restrict__ mask,
            const __hip_bfloat16* __restrict__ vtg, __hip_bfloat16* __restrict__ attnb) {
    constexpr int PS = 296;
    __shared__ __hip_bfloat16 P[4][16 * PS];
    const int tid = threadIdx.x, wave = tid >> 6, lane = tid & 63;
    const int bh = blockIdx.y, b = bh >> 4, h = bh & 15;
    const int q0 = blockIdx.x * 64 + wave * 16;
    const int lo = lane & 15, hi = lane >> 4;

    short8 qf0, qf1;
    {
        const __hip_bfloat16* qb = qkv + (size_t)(b * L_ + q0 + lo) * NQKV + h * DH + hi * 8;
        qf0 = *(const short8*)qb;
        qf1 = *(const short8*)(qb + 32);
    }

    floatx4 sc[17];
    const __hip_bfloat16* kcol = qkv + (size_t)b * L_ * NQKV + D_ + h * DH + hi * 8;
#pragma unroll
    for (int t = 0; t < 17; t++) {
        int jg = q0 - 128 + t * 16 + lo;
        int jc = jg < 0 ? 0 : (jg >= L_ ? L_ - 1 : jg);
        const __hip_bfloat16* kb = kcol + (size_t)jc * NQKV;
        short8 kf0 = *(const short8*)kb;
        short8 kf1 = *(const short8*)(kb + 32);
        floatx4 a = {};
        a = __builtin_amdgcn_mfma_f32_16x16x32_bf16(qf0, kf0, a, 0, 0, 0);
        a = __builtin_amdgcn_mfma_f32_16x16x32_bf16(qf1, kf1, a, 0, 0, 0);
        float mval = mask[b * L_ + jc];
        bool jok = (jg >= 0) && (jg < L_) && (mval == 0.0f);
#pragma unroll
        for (int r = 0; r < 4; r++) {
            int qi = q0 + hi * 4 + r;
            bool ok = jok && (jg >= qi - 128) && (jg <= qi + 128);
            a[r] = ok ? a[r] * 0.125f : -1e9f;
        }
        sc[t] = a;
    }

#pragma unroll
    for (int r = 0; r < 4; r++) {
        float m = -3e38f;
#pragma unroll
        for (int t = 0; t < 17; t++) m = fmaxf(m, sc[t][r]);
        m = fmaxf(m, __shfl_xor(m, 1));
        m = fmaxf(m, __shfl_xor(m, 2));
        m = fmaxf(m, __shfl_xor(m, 4));
        m = fmaxf(m, __shfl_xor(m, 8));
        float s = 0.0f;
#pragma unroll
        for (int t = 0; t < 17; t++) { float e = __expf(sc[t][r] - m); sc[t][r] = e; s += e; }
        s += __shfl_xor(s, 1); s += __shfl_xor(s, 2);
        s += __shfl_xor(s, 4); s += __shfl_xor(s, 8);
        float inv = 1.0f / s;
#pragma unroll
        for (int t = 0; t < 17; t++) sc[t][r] *= inv;
    }

    __hip_bfloat16* Pw = &P[wave][0];
#pragma unroll
    for (int t = 0; t < 17; t++)
#pragma unroll
        for (int r = 0; r < 4; r++)
            Pw[(hi * 4 + r) * PS + t * 16 + lo] = __float2bfloat16(sc[t][r]);
    {
        int zr = lane >> 2, zc = 272 + (lane & 3) * 4;
        __hip_bfloat16 z = __float2bfloat16(0.0f);
#pragma unroll
        for (int i = 0; i < 4; i++) Pw[zr * PS + zc + i] = z;
    }

    floatx4 o[4] = {};
#pragma unroll
    for (int st = 0; st < 9; st++) {
        short8 pa = *(const short8*)(Pw + lo * PS + st * 32 + hi * 8);
        int jb = q0 - 128 + st * 32 + hi * 8;
#pragma unroll
        for (int dt = 0; dt < 4; dt++) {
            const __hip_bfloat16* vb = vtg + (long)(bh * DH + dt * 16 + lo) * L_ + jb;
            short8 vf = *(const short8*)vb;
            o[dt] = __builtin_amdgcn_mfma_f32_16x16x32_bf16(pa, vf, o[dt], 0, 0, 0);
        }
    }

#pragma unroll
    for (int dt = 0; dt < 4; dt++)
#pragma unroll
        for (int r = 0; r < 4; r++) {
            int row = q0 + hi * 4 + r;
            attnb[(size_t)(b * L_ + row) * D_ + h * DH + dt * 16 + lo] =
                __float2bfloat16(o[dt][r]);
        }
}

// ---------------- residual + LayerNorm ----------------
__global__ __launch_bounds__(256)
void k_ln(const float* __restrict__ x, const __hip_bfloat16* __restrict__ attnb,
          const float* __restrict__ g, const float* __restrict__ bt,
          __hip_bfloat16* __restrict__ hb) {
    const int row = blockIdx.x, tid = threadIdx.x;
    const int c4 = tid * 4;
    float4 xv = *(const float4*)(x + (size_t)row * D_ + c4);
    short4v av = *(const short4v*)(attnb + (size_t)row * D_ + c4);
    float h0 = xv.x + b2f((unsigned short)av[0]);
    float h1 = xv.y + b2f((unsigned short)av[1]);
    float h2 = xv.z + b2f((unsigned short)av[2]);
    float h3 = xv.w + b2f((unsigned short)av[3]);
    float s = h0 + h1 + h2 + h3;
    float q = h0 * h0 + h1 * h1 + h2 * h2 + h3 * h3;
#pragma unroll
    for (int off = 32; off > 0; off >>= 1) {
        s += __shfl_down(s, off);
        q += __shfl_down(q, off);
    }
    __shared__ float red[8];
    int wave = tid >> 6, lane = tid & 63;
    if (lane == 0) { red[wave] = s; red[4 + wave] = q; }
    __syncthreads();
    s = red[0] + red[1] + red[2] + red[3];
    q = red[4] + red[5] + red[6] + red[7];
    float mu = s * (1.0f / D_);
    float var = q * (1.0f / D_) - mu * mu;
    float inv = rsqrtf(var + 1e-5f);
    float4 gv = *(const float4*)(g + c4);
    float4 bv = *(const float4*)(bt + c4);
    alignas(8) __hip_bfloat16 ov[4];
    ov[0] = __float2bfloat16((h0 - mu) * inv * gv.x + bv.x);
    ov[1] = __float2bfloat16((h1 - mu) * inv * gv.y + bv.y);
    ov[2] = __float2bfloat16((h2 - mu) * inv * gv.z + bv.z);
    ov[3] = __float2bfloat16((h3 - mu) * inv * gv.w + bv.w);
    *(short4v*)(hb + (size_t)row * D_ + c4) = *(const short4v*)ov;
}

// ---------------- launch ----------------
extern "C" void kernel_launch(void* const* d_in, const int* in_sizes, int n_in,
                              void* d_out, int out_size, void* d_ws, size_t ws_size,
                              hipStream_t stream) {
    const float* x    = (const float*)d_in[0];
    const float* mask = (const float*)d_in[1];
    const float* Wq   = (const float*)d_in[2];
    const float* bq   = (const float*)d_in[3];
    const float* Wk   = (const float*)d_in[4];
    const float* bk   = (const float*)d_in[5];
    const float* Wv   = (const float*)d_in[6];
    const float* bv   = (const float*)d_in[7];
    const float* ln_g = (const float*)d_in[8];
    const float* ln_b = (const float*)d_in[9];
    const float* W1   = (const float*)d_in[10];
    const float* b1   = (const float*)d_in[11];
    const float* W2   = (const float*)d_in[12];
    const float* b2   = (const float*)d_in[13];
    float* out = (float*)d_out;
    char* ws = (char*)d_ws;

    __hip_bfloat16* xb   = (__hip_bfloat16*)(ws + OFF_XB);
    __hip_bfloat16* wct  = (__hip_bfloat16*)(ws + OFF_WCT);
    __hip_bfloat16* w1t  = (__hip_bfloat16*)(ws + OFF_W1T);
    __hip_bfloat16* w2t  = (__hip_bfloat16*)(ws + OFF_W2T);
    __hip_bfloat16* qkvb = (__hip_bfloat16*)(ws + OFF_QKV);
    __hip_bfloat16* vtg  = (__hip_bfloat16*)(ws + OFF_VT) + VT_GUARD;
    __hip_bfloat16* attb = (__hip_bfloat16*)(ws + OFF_ATT);
    __hip_bfloat16* hb   = (__hip_bfloat16*)(ws + OFF_HB);
    __hip_bfloat16* midb = (__hip_bfloat16*)(ws + OFF_MID);

    // input conversions
    k_cvt_x<<<(M_ * D_) / 2048, 256, 0, stream>>>(x, xb);
    k_tcvt<<<dim3(D_ / 64, D_ / 64), 256, 0, stream>>>(Wq, wct,                   D_, D_);
    k_tcvt<<<dim3(D_ / 64, D_ / 64), 256, 0, stream>>>(Wk, wct + 1024 * 1024,     D_, D_);
    k_tcvt<<<dim3(D_ / 64, D_ / 64), 256, 0, stream>>>(Wv, wct + 2 * 1024 * 1024, D_, D_);
    k_tcvt<<<dim3(F_ / 64, D_ / 64), 256, 0, stream>>>(W1, w1t, D_, F_);
    k_tcvt<<<dim3(D_ / 64, F_ / 64), 256, 0, stream>>>(W2, w2t, F_, D_);

    // fused QKV projection: BM=256, BN=128 -> grid 32*24 = 768
    k_g8<2, 4, 0, D_, 24><<<768, 512, 0, stream>>>(
        xb, wct, bq, bk, bv, qkvb, nullptr, nullptr);

    // V transpose, attention
    k_vtrans<<<dim3(L_ / 64, B_ * H_), 256, 0, stream>>>(qkvb, vtg);
    k_attn<<<dim3(L_ / 64, B_ * H_), 256, 0, stream>>>(qkvb, mask, vtg, attb);

    // residual + LN
    k_ln<<<M_, 256, 0, stream>>>(x, attb, ln_g, ln_b, hb);

    // FFN1: BM=256, BN=256 -> grid 32*16 = 512
    k_g8<4, 4, 1, D_, 16><<<512, 512, 0, stream>>>(
        hb, w1t, b1, nullptr, nullptr, midb, nullptr, nullptr);
    // FFN2: BM=256, BN=128 -> grid 32*8 = 256
    k_g8<2, 4, 2, F_, 8><<<256, 512, 0, stream>>>(
        midb, w2t, b2, nullptr, nullptr, nullptr, out, hb);
}

// Round 6
// 500.854 us; speedup vs baseline: 1.0971x; 1.0091x over previous
//
#include <hip/hip_runtime.h>
#include <hip/hip_bf16.h>
#include <cstdint>

typedef __attribute__((ext_vector_type(8))) short short8;
typedef __attribute__((ext_vector_type(4))) short short4v;
typedef __attribute__((ext_vector_type(4))) float floatx4;

constexpr int B_ = 2, L_ = 4096, D_ = 1024, H_ = 16, DH = 64, F_ = 4096;
constexpr int M_ = B_ * L_;        // 8192 rows
constexpr int NQKV = 3 * D_;       // 3072
constexpr int VT_GUARD = 512;

// ---------------- workspace layout (bytes) ----------------
constexpr size_t OFF_XB  = 0;                                       // bf16 [M][D]
constexpr size_t OFF_WCT = OFF_XB  + (size_t)M_ * D_ * 2;           // bf16 [3072][1024]
constexpr size_t OFF_W1T = OFF_WCT + (size_t)NQKV * D_ * 2;         // bf16 [4096][1024]
constexpr size_t OFF_W2T = OFF_W1T + (size_t)F_ * D_ * 2;           // bf16 [1024][4096]
constexpr size_t OFF_QKV = OFF_W2T + (size_t)D_ * F_ * 2;           // bf16 [M][3072]
constexpr size_t OFF_VT  = OFF_QKV + (size_t)M_ * NQKV * 2;
constexpr size_t OFF_ATT = OFF_VT  + ((size_t)B_*H_*DH*L_ + 2*VT_GUARD) * 2;
constexpr size_t OFF_HB  = OFF_ATT + (size_t)M_ * D_ * 2;
constexpr size_t OFF_MID = OFF_HB  + (size_t)M_ * D_ * 2;           // bf16 [M][F]

static __device__ __forceinline__ float b2f(unsigned short u) {
    union { unsigned int i; float f; } v; v.i = ((unsigned int)u) << 16; return v.f;
}

static __device__ __forceinline__ void gload16(const void* g, void* l) {
    __builtin_amdgcn_global_load_lds(
        (const __attribute__((address_space(1))) uint32_t*)g,
        (__attribute__((address_space(3))) uint32_t*)l, 16, 0, 0);
}

template<int N> static __device__ __forceinline__ void waitvm() {
    if constexpr (N == 2)      asm volatile("s_waitcnt vmcnt(2)" ::: "memory");
    else if constexpr (N == 6) asm volatile("s_waitcnt vmcnt(6)" ::: "memory");
    else if constexpr (N == 8) asm volatile("s_waitcnt vmcnt(8)" ::: "memory");
    else                       asm volatile("s_waitcnt vmcnt(0)" ::: "memory");
}

// ---------------- f32 -> bf16 convert (x) ----------------
__global__ __launch_bounds__(256) void k_cvt_x(const float* __restrict__ x,
                                               __hip_bfloat16* __restrict__ xb) {
    int i = (blockIdx.x * 256 + threadIdx.x) * 8;
    float4 a = *(const float4*)(x + i);
    float4 b = *(const float4*)(x + i + 4);
    alignas(16) __hip_bfloat16 t[8];
    t[0] = __float2bfloat16(a.x); t[1] = __float2bfloat16(a.y);
    t[2] = __float2bfloat16(a.z); t[3] = __float2bfloat16(a.w);
    t[4] = __float2bfloat16(b.x); t[5] = __float2bfloat16(b.y);
    t[6] = __float2bfloat16(b.z); t[7] = __float2bfloat16(b.w);
    *(uint4*)(xb + i) = *(const uint4*)t;
}

// ---------------- transpose+convert: in [R][C] f32 -> out [C][R] bf16 ----------------
__global__ __launch_bounds__(256) void k_tcvt(const float* __restrict__ in,
                                              __hip_bfloat16* __restrict__ out,
                                              int R, int C) {
    __shared__ float t[64][65];
    int tx = threadIdx.x & 63, ty4 = threadIdx.x >> 6;
    int c0 = blockIdx.x * 64, r0 = blockIdx.y * 64;
#pragma unroll
    for (int i = 0; i < 16; i++) {
        int r = ty4 + i * 4;
        t[r][tx] = in[(size_t)(r0 + r) * C + c0 + tx];
    }
    __syncthreads();
#pragma unroll
    for (int i = 0; i < 16; i++) {
        int r = ty4 + i * 4;
        out[(size_t)(c0 + r) * R + r0 + tx] = __float2bfloat16(t[tx][r]);
    }
}

// ---------------- V transpose ----------------
__global__ __launch_bounds__(256) void k_vtrans(const __hip_bfloat16* __restrict__ qkv,
                                                __hip_bfloat16* __restrict__ vtg) {
    __shared__ __hip_bfloat16 t[64][72];
    int tx = threadIdx.x & 63, ty4 = threadIdx.x >> 6;
    int bh = blockIdx.y, b = bh >> 4, h = bh & 15;
    int j0 = blockIdx.x * 64;
#pragma unroll
    for (int i = 0; i < 16; i++) {
        int j = ty4 + i * 4;
        t[j][tx] = qkv[(size_t)(b * L_ + j0 + j) * NQKV + 2 * D_ + h * DH + tx];
    }
    __syncthreads();
#pragma unroll
    for (int i = 0; i < 16; i++) {
        int d = ty4 + i * 4;
        vtg[(long)(bh * DH + d) * L_ + j0 + tx] = t[tx][d];
    }
}

// ---------------- 256xBN 8-wave phase-template GEMM, deep-prefetch staging ----------------
// C[8192][NBN*BN] = A[8192][KTOT] * BT[NBN*BN][KTOT]^T,  BN = NFRAG*64.
// 512 thr = 8 waves (2m x 4n); per-wave 128 x NFRAG*16 output.
// NPH phases per K-tile (NPH=4 for NFRAG=4, NPH=2 for NFRAG=2), 16 MFMA/phase.
// ALL of tile t+1's loads issued at phase 0 of tile t (order B..., A0,A2, A1,A3).
// Counted vmcnt: NFRAG=4: vmcnt(8)@end-ph1 (5-phase headroom), vmcnt(2)@end-ph3 (4-phase).
//                NFRAG=2: vmcnt(6)@end-ph0, vmcnt(2)@end-ph1 (2-phase headroom).
// Never vmcnt(0) in the main loop. LDS rows 128B, 8-chunk XOR swizzle both sides.
template<int NFRAG, int GM, int EPI, int KTOT, int NBN>
__global__ __launch_bounds__(512, 2)
void k_g8(const __hip_bfloat16* __restrict__ A, const __hip_bfloat16* __restrict__ BT,
          const float* __restrict__ b0p, const float* __restrict__ b1p,
          const float* __restrict__ b2p,
          __hip_bfloat16* __restrict__ obf, float* __restrict__ of32,
          const __hip_bfloat16* __restrict__ hres) {
    constexpr int BN = NFRAG * 64;
    constexpr int KT = KTOT / 64;
    constexpr int PER = GM * NBN;
    constexpr int NPH = (NFRAG == 4) ? 4 : 2;   // phases per K-tile
    constexpr int MPF = 8 / NPH;                // m-frags per phase

    __shared__ __hip_bfloat16 AS[2][4 * 4096];
    __shared__ __hip_bfloat16 BS[2][NFRAG * 4096];

    const int tid = threadIdx.x, wave = tid >> 6, lane = tid & 63;
    const int lo = lane & 15, hi = lane >> 4;
    const int wm = wave >> 2, wn = wave & 3;

    // bijective XCD swizzle + group-major (GM bm-rows per group)
    const int nwg = gridDim.x, q = nwg >> 3;
    const int bid = blockIdx.x;
    const int swz = (bid & 7) * q + (bid >> 3);
    const int g = swz / PER, r = swz % PER;
    const int bm = g * GM + (r % GM);
    const int bn = r / GM;
    const size_t m0 = (size_t)bm * 256, n0 = (size_t)bn * BN;

    // staging: thread covers row srow (within 64-row sweep); global chunk pre-swizzled
    const int srow = tid >> 3;
    const int gcc = (tid & 7) ^ (srow & 7);
    const __hip_bfloat16* aG = A  + (m0 + srow) * (size_t)KTOT + gcc * 8;
    const __hip_bfloat16* bG = BT + (n0 + srow) * (size_t)KTOT + gcc * 8;
    const int ldst = wave * 512;    // element offset inside sweep region (+lane*8 by HW)

    // fragment read: addr(elem) = R*64 + ((k*4+hi)^(R&7))*8 ; R&7 == lo&7
    int ccr[2];
#pragma unroll
    for (int k = 0; k < 2; ++k) ccr[k] = ((k * 4 + hi) ^ (lo & 7)) * 8;
    const int Ra = wm * 128 + lo;       // A base row for this thread
    const int Rb0 = wn * (NFRAG * 16) + lo;

    floatx4 acc[8][NFRAG] = {};

#define STG_A(buf, sw, tn) gload16(aG + (size_t)(sw) * 64 * KTOT + (size_t)(tn) * 64, \
                                   &AS[buf][(sw) * 4096 + ldst])
#define STG_B(buf, sw, tn) gload16(bG + (size_t)(sw) * 64 * KTOT + (size_t)(tn) * 64, \
                                   &BS[buf][(sw) * 4096 + ldst])
    // issue order matters for vmcnt counts: B sweeps, then A0,A2, then A1,A3 (youngest)
#define STG_ALL(buf, tn)                                                     \
    do {                                                                     \
        STG_B(buf, 0, tn); STG_B(buf, 1, tn);                                \
        if constexpr (NFRAG == 4) { STG_B(buf, 2, tn); STG_B(buf, 3, tn); }  \
        STG_A(buf, 0, tn); STG_A(buf, 2, tn);                                \
        STG_A(buf, 1, tn); STG_A(buf, 3, tn);                                \
    } while (0)

    // prologue: stage tile 0, drain, barrier
    STG_ALL(0, 0);
    asm volatile("s_waitcnt vmcnt(0)" ::: "memory");
    __builtin_amdgcn_s_barrier();

    for (int t = 0; t < KT; ++t) {
        const int cur = t & 1, nxt = cur ^ 1;
        const int tn = (t + 1 < KT) ? (t + 1) : t;   // tail: re-stage resident tile (L2-hot)
        const __hip_bfloat16* aL = &AS[cur][0];
        const __hip_bfloat16* bL = &BS[cur][0];
        short8 bfr[NFRAG][2];

#pragma unroll
        for (int p = 0; p < NPH; ++p) {
            short8 afr[MPF][2];
            if (p == 0) {
#pragma unroll
                for (int gf = 0; gf < NFRAG; ++gf)
#pragma unroll
                    for (int k = 0; k < 2; ++k)
                        bfr[gf][k] = *(const short8*)(bL + (Rb0 + gf * 16) * 64 + ccr[k]);
            }
#pragma unroll
            for (int f = 0; f < MPF; ++f)
#pragma unroll
                for (int k = 0; k < 2; ++k)
                    afr[f][k] = *(const short8*)(aL + (Ra + (p * MPF + f) * 16) * 64 + ccr[k]);
            if (p == 0) STG_ALL(nxt, tn);
            __builtin_amdgcn_s_barrier();
            __builtin_amdgcn_s_setprio(1);
#pragma unroll
            for (int f = 0; f < MPF; ++f)
#pragma unroll
                for (int gf = 0; gf < NFRAG; ++gf)
#pragma unroll
                    for (int k = 0; k < 2; ++k)
                        acc[p * MPF + f][gf] = __builtin_amdgcn_mfma_f32_16x16x32_bf16(
                            afr[f][k], bfr[gf][k], acc[p * MPF + f][gf], 0, 0, 0);
            __builtin_amdgcn_s_setprio(0);
            if constexpr (NPH == 4) {
                if (p == 1) waitvm<8>();
                if (p == 3) waitvm<2>();
            } else {
                if (p == 0) waitvm<6>();
                if (p == 1) waitvm<2>();
            }
            __builtin_amdgcn_s_barrier();
        }
    }
#undef STG_A
#undef STG_B
#undef STG_ALL

    // ---- epilogue ----
#pragma unroll
    for (int mf = 0; mf < 8; ++mf) {
        const int row = (int)m0 + wm * 128 + mf * 16 + hi * 4;
#pragma unroll
        for (int gf = 0; gf < NFRAG; ++gf) {
            const int col = (int)n0 + wn * (NFRAG * 16) + gf * 16 + lo;
#pragma unroll
            for (int rr = 0; rr < 4; ++rr) {
                float v = acc[mf][gf][rr];
                const size_t ro = (size_t)(row + rr);
                if (EPI == 0) {
                    float bia = (col < 1024) ? b0p[col]
                              : (col < 2048 ? b1p[col - 1024] : b2p[col - 2048]);
                    obf[ro * NQKV + col] = __float2bfloat16(v + bia);
                } else if (EPI == 1) {
                    v += b0p[col];
                    v = 0.5f * v * (1.0f + erff(v * 0.70710678118654752440f));
                    obf[ro * F_ + col] = __float2bfloat16(v);
                } else {
                    v += b0p[col];
                    v += b2f(*(const unsigned short*)&hres[ro * D_ + col]);
                    of32[ro * D_ + col] = v;
                }
            }
        }
    }
}

// ---------------- sliding-window attention (unchanged, verified) ----------------
__global__ __launch_bounds__(256, 2)
void k_attn(const __hip_bfloat16* __restrict__ qkv, const float* __restrict__ mask,
            const __hip_bfloat16* __restrict__ vtg, __hip_bfloat16* __restrict__ attnb) {
    constexpr int PS = 296;
    __shared__ __hip_bfloat16 P[4][16 * PS];
    const int tid = threadIdx.x, wave = tid >> 6, lane = tid & 63;
    const int bh = blockIdx.y, b = bh >> 4, h = bh & 15;
    const int q0 = blockIdx.x * 64 + wave * 16;
    const int lo = lane & 15, hi = lane >> 4;

    short8 qf0, qf1;
    {
        const __hip_bfloat16* qb = qkv + (size_t)(b * L_ + q0 + lo) * NQKV + h * DH + hi * 8;
        qf0 = *(const short8*)qb;
        qf1 = *(const short8*)(qb + 32);
    }

    floatx4 sc[17];
    const __hip_bfloat16* kcol = qkv + (size_t)b * L_ * NQKV + D_ + h * DH + hi * 8;
#pragma unroll
    for (int t = 0; t < 17; t++) {
        int jg = q0 - 128 + t * 16 + lo;
        int jc = jg < 0 ? 0 : (jg >= L_ ? L_ - 1 : jg);
        const __hip_bfloat16* kb = kcol + (size_t)jc * NQKV;
        short8 kf0 = *(const short8*)kb;
        short8 kf1 = *(const short8*)(kb + 32);
        floatx4 a = {};
        a = __builtin_amdgcn_mfma_f32_16x16x32_bf16(qf0, kf0, a, 0, 0, 0);
        a = __builtin_amdgcn_mfma_f32_16x16x32_bf16(qf1, kf1, a, 0, 0, 0);
        float mval = mask[b * L_ + jc];
        bool jok = (jg >= 0) && (jg < L_) && (mval == 0.0f);
#pragma unroll
        for (int r = 0; r < 4; r++) {
            int qi = q0 + hi * 4 + r;
            bool ok = jok && (jg >= qi - 128) && (jg <= qi + 128);
            a[r] = ok ? a[r] * 0.125f : -1e9f;
        }
        sc[t] = a;
    }

#pragma unroll
    for (int r = 0; r < 4; r++) {
        float m = -3e38f;
#pragma unroll
        for (int t = 0; t < 17; t++) m = fmaxf(m, sc[t][r]);
        m = fmaxf(m, __shfl_xor(m, 1));
        m = fmaxf(m, __shfl_xor(m, 2));
        m = fmaxf(m, __shfl_xor(m, 4));
        m = fmaxf(m, __shfl_xor(m, 8));
        float s = 0.0f;
#pragma unroll
        for (int t = 0; t < 17; t++) { float e = __expf(sc[t][r] - m); sc[t][r] = e; s += e; }
        s += __shfl_xor(s, 1); s += __shfl_xor(s, 2);
        s += __shfl_xor(s, 4); s += __shfl_xor(s, 8);
        float inv = 1.0f / s;
#pragma unroll
        for (int t = 0; t < 17; t++) sc[t][r] *= inv;
    }

    __hip_bfloat16* Pw = &P[wave][0];
#pragma unroll
    for (int t = 0; t < 17; t++)
#pragma unroll
        for (int r = 0; r < 4; r++)
            Pw[(hi * 4 + r) * PS + t * 16 + lo] = __float2bfloat16(sc[t][r]);
    {
        int zr = lane >> 2, zc = 272 + (lane & 3) * 4;
        __hip_bfloat16 z = __float2bfloat16(0.0f);
#pragma unroll
        for (int i = 0; i < 4; i++) Pw[zr * PS + zc + i] = z;
    }

    floatx4 o[4] = {};
#pragma unroll
    for (int st = 0; st < 9; st++) {
        short8 pa = *(const short8*)(Pw + lo * PS + st * 32 + hi * 8);
        int jb = q0 - 128 + st * 32 + hi * 8;
#pragma unroll
        for (int dt = 0; dt < 4; dt++) {
            const __hip_bfloat16* vb = vtg + (long)(bh * DH + dt * 16 + lo) * L_ + jb;
            short8 vf = *(const short8*)vb;
            o[dt] = __builtin_amdgcn_mfma_f32_16x16x32_bf16(pa, vf, o[dt], 0, 0, 0);
        }
    }

#pragma unroll
    for (int dt = 0; dt < 4; dt++)
#pragma unroll
        for (int r = 0; r < 4; r++) {
            int row = q0 + hi * 4 + r;
            attnb[(size_t)(b * L_ + row) * D_ + h * DH + dt * 16 + lo] =
                __float2bfloat16(o[dt][r]);
        }
}

// ---------------- residual + LayerNorm ----------------
__global__ __launch_bounds__(256)
void k_ln(const float* __restrict__ x, const __hip_bfloat16* __restrict__ attnb,
          const float* __restrict__ g, const float* __restrict__ bt,
          __hip_bfloat16* __restrict__ hb) {
    const int row = blockIdx.x, tid = threadIdx.x;
    const int c4 = tid * 4;
    float4 xv = *(const float4*)(x + (size_t)row * D_ + c4);
    short4v av = *(const short4v*)(attnb + (size_t)row * D_ + c4);
    float h0 = xv.x + b2f((unsigned short)av[0]);
    float h1 = xv.y + b2f((unsigned short)av[1]);
    float h2 = xv.z + b2f((unsigned short)av[2]);
    float h3 = xv.w + b2f((unsigned short)av[3]);
    float s = h0 + h1 + h2 + h3;
    float q = h0 * h0 + h1 * h1 + h2 * h2 + h3 * h3;
#pragma unroll
    for (int off = 32; off > 0; off >>= 1) {
        s += __shfl_down(s, off);
        q += __shfl_down(q, off);
    }
    __shared__ float red[8];
    int wave = tid >> 6, lane = tid & 63;
    if (lane == 0) { red[wave] = s; red[4 + wave] = q; }
    __syncthreads();
    s = red[0] + red[1] + red[2] + red[3];
    q = red[4] + red[5] + red[6] + red[7];
    float mu = s * (1.0f / D_);
    float var = q * (1.0f / D_) - mu * mu;
    float inv = rsqrtf(var + 1e-5f);
    float4 gv = *(const float4*)(g + c4);
    float4 bv = *(const float4*)(bt + c4);
    alignas(8) __hip_bfloat16 ov[4];
    ov[0] = __float2bfloat16((h0 - mu) * inv * gv.x + bv.x);
    ov[1] = __float2bfloat16((h1 - mu) * inv * gv.y + bv.y);
    ov[2] = __float2bfloat16((h2 - mu) * inv * gv.z + bv.z);
    ov[3] = __float2bfloat16((h3 - mu) * inv * gv.w + bv.w);
    *(short4v*)(hb + (size_t)row * D_ + c4) = *(const short4v*)ov;
}

// ---------------- launch ----------------
extern "C" void kernel_launch(void* const* d_in, const int* in_sizes, int n_in,
                              void* d_out, int out_size, void* d_ws, size_t ws_size,
                              hipStream_t stream) {
    const float* x    = (const float*)d_in[0];
    const float* mask = (const float*)d_in[1];
    const float* Wq   = (const float*)d_in[2];
    const float* bq   = (const float*)d_in[3];
    const float* Wk   = (const float*)d_in[4];
    const float* bk   = (const float*)d_in[5];
    const float* Wv   = (const float*)d_in[6];
    const float* bv   = (const float*)d_in[7];
    const float* ln_g = (const float*)d_in[8];
    const float* ln_b = (const float*)d_in[9];
    const float* W1   = (const float*)d_in[10];
    const float* b1   = (const float*)d_in[11];
    const float* W2   = (const float*)d_in[12];
    const float* b2   = (const float*)d_in[13];
    float* out = (float*)d_out;
    char* ws = (char*)d_ws;

    __hip_bfloat16* xb   = (__hip_bfloat16*)(ws + OFF_XB);
    __hip_bfloat16* wct  = (__hip_bfloat16*)(ws + OFF_WCT);
    __hip_bfloat16* w1t  = (__hip_bfloat16*)(ws + OFF_W1T);
    __hip_bfloat16* w2t  = (__hip_bfloat16*)(ws + OFF_W2T);
    __hip_bfloat16* qkvb = (__hip_bfloat16*)(ws + OFF_QKV);
    __hip_bfloat16* vtg  = (__hip_bfloat16*)(ws + OFF_VT) + VT_GUARD;
    __hip_bfloat16* attb = (__hip_bfloat16*)(ws + OFF_ATT);
    __hip_bfloat16* hb   = (__hip_bfloat16*)(ws + OFF_HB);
    __hip_bfloat16* midb = (__hip_bfloat16*)(ws + OFF_MID);

    // input conversions
    k_cvt_x<<<(M_ * D_) / 2048, 256, 0, stream>>>(x, xb);
    k_tcvt<<<dim3(D_ / 64, D_ / 64), 256, 0, stream>>>(Wq, wct,                   D_, D_);
    k_tcvt<<<dim3(D_ / 64, D_ / 64), 256, 0, stream>>>(Wk, wct + 1024 * 1024,     D_, D_);
    k_tcvt<<<dim3(D_ / 64, D_ / 64), 256, 0, stream>>>(Wv, wct + 2 * 1024 * 1024, D_, D_);
    k_tcvt<<<dim3(F_ / 64, D_ / 64), 256, 0, stream>>>(W1, w1t, D_, F_);
    k_tcvt<<<dim3(D_ / 64, F_ / 64), 256, 0, stream>>>(W2, w2t, F_, D_);

    // fused QKV projection: BM=256, BN=128 -> grid 32*24 = 768
    k_g8<2, 4, 0, D_, 24><<<768, 512, 0, stream>>>(
        xb, wct, bq, bk, bv, qkvb, nullptr, nullptr);

    // V transpose, attention
    k_vtrans<<<dim3(L_ / 64, B_ * H_), 256, 0, stream>>>(qkvb, vtg);
    k_attn<<<dim3(L_ / 64, B_ * H_), 256, 0, stream>>>(qkvb, mask, vtg, attb);

    // residual + LN
    k_ln<<<M_, 256, 0, stream>>>(x, attb, ln_g, ln_b, hb);

    // FFN1: BM=256, BN=256 -> grid 32*16 = 512
    k_g8<4, 4, 1, D_, 16><<<512, 512, 0, stream>>>(
        hb, w1t, b1, nullptr, nullptr, midb, nullptr, nullptr);
    // FFN2: BM=256, BN=128 -> grid 32*8 = 256 ; GM=1 keeps per-XCD A-panel at 2MB (L2-fit)
    k_g8<2, 1, 2, F_, 8><<<256, 512, 0, stream>>>(
        midb, w2t, b2, nullptr, nullptr, nullptr, out, hb);
}

// Round 8
// 490.251 us; speedup vs baseline: 1.1208x; 1.0216x over previous
//
#include <hip/hip_runtime.h>
#include <hip/hip_bf16.h>
#include <cstdint>

typedef __attribute__((ext_vector_type(8))) short short8;
typedef __attribute__((ext_vector_type(4))) short short4v;
typedef __attribute__((ext_vector_type(4))) float floatx4;

constexpr int B_ = 2, L_ = 4096, D_ = 1024, H_ = 16, DH = 64, F_ = 4096;
constexpr int M_ = B_ * L_;        // 8192 rows
constexpr int NQKV = 3 * D_;       // 3072
constexpr int VT_GUARD = 512;

// ---------------- workspace layout (bytes) ----------------
constexpr size_t OFF_XB  = 0;                                       // bf16 [M][D]
constexpr size_t OFF_WCT = OFF_XB  + (size_t)M_ * D_ * 2;           // bf16 [3072][1024]
constexpr size_t OFF_W1T = OFF_WCT + (size_t)NQKV * D_ * 2;         // bf16 [4096][1024]
constexpr size_t OFF_W2T = OFF_W1T + (size_t)F_ * D_ * 2;           // bf16 [1024][4096]
constexpr size_t OFF_QKV = OFF_W2T + (size_t)D_ * F_ * 2;           // bf16 [M][3072]
constexpr size_t OFF_VT  = OFF_QKV + (size_t)M_ * NQKV * 2;
constexpr size_t OFF_ATT = OFF_VT  + ((size_t)B_*H_*DH*L_ + 2*VT_GUARD) * 2;
constexpr size_t OFF_HB  = OFF_ATT + (size_t)M_ * D_ * 2;
constexpr size_t OFF_MID = OFF_HB  + (size_t)M_ * D_ * 2;           // bf16 [M][F]

static __device__ __forceinline__ float b2f(unsigned short u) {
    union { unsigned int i; float f; } v; v.i = ((unsigned int)u) << 16; return v.f;
}

static __device__ __forceinline__ void gload16(const void* g, void* l) {
    __builtin_amdgcn_global_load_lds(
        (const __attribute__((address_space(1))) uint32_t*)g,
        (__attribute__((address_space(3))) uint32_t*)l, 16, 0, 0);
}

// ---------------- f32 -> bf16 convert (x) ----------------
__global__ __launch_bounds__(256) void k_cvt_x(const float* __restrict__ x,
                                               __hip_bfloat16* __restrict__ xb) {
    int i = (blockIdx.x * 256 + threadIdx.x) * 8;
    float4 a = *(const float4*)(x + i);
    float4 b = *(const float4*)(x + i + 4);
    alignas(16) __hip_bfloat16 t[8];
    t[0] = __float2bfloat16(a.x); t[1] = __float2bfloat16(a.y);
    t[2] = __float2bfloat16(a.z); t[3] = __float2bfloat16(a.w);
    t[4] = __float2bfloat16(b.x); t[5] = __float2bfloat16(b.y);
    t[6] = __float2bfloat16(b.z); t[7] = __float2bfloat16(b.w);
    *(uint4*)(xb + i) = *(const uint4*)t;
}

// ---------------- transpose+convert: in [R][C] f32 -> out [C][R] bf16 ----------------
__global__ __launch_bounds__(256) void k_tcvt(const float* __restrict__ in,
                                              __hip_bfloat16* __restrict__ out,
                                              int R, int C) {
    __shared__ float t[64][65];
    int tx = threadIdx.x & 63, ty4 = threadIdx.x >> 6;
    int c0 = blockIdx.x * 64, r0 = blockIdx.y * 64;
#pragma unroll
    for (int i = 0; i < 16; i++) {
        int r = ty4 + i * 4;
        t[r][tx] = in[(size_t)(r0 + r) * C + c0 + tx];
    }
    __syncthreads();
#pragma unroll
    for (int i = 0; i < 16; i++) {
        int r = ty4 + i * 4;
        out[(size_t)(c0 + r) * R + r0 + tx] = __float2bfloat16(t[tx][r]);
    }
}

// ---------------- V transpose ----------------
__global__ __launch_bounds__(256) void k_vtrans(const __hip_bfloat16* __restrict__ qkv,
                                                __hip_bfloat16* __restrict__ vtg) {
    __shared__ __hip_bfloat16 t[64][72];
    int tx = threadIdx.x & 63, ty4 = threadIdx.x >> 6;
    int bh = blockIdx.y, b = bh >> 4, h = bh & 15;
    int j0 = blockIdx.x * 64;
#pragma unroll
    for (int i = 0; i < 16; i++) {
        int j = ty4 + i * 4;
        t[j][tx] = qkv[(size_t)(b * L_ + j0 + j) * NQKV + 2 * D_ + h * DH + tx];
    }
    __syncthreads();
#pragma unroll
    for (int i = 0; i < 16; i++) {
        int d = ty4 + i * 4;
        vtg[(long)(bh * DH + d) * L_ + j0 + tx] = t[tx][d];
    }
}

// ---------------- 128xBN BK=32 triple-buffered pipeline GEMM ----------------
// C[8192][NBN*BN] = A[8192][KTOT] * BT[NBN*BN][KTOT]^T,  BN = WN*64.
// NT threads = NT/64 waves (2m x WN n); per-wave 64x64 output (acc[4][4]).
// Triple-buffered LDS: stage tile t+2 during tile t (2-tile latency headroom).
// ONE barrier + ONE counted vmcnt(LPT) per K-tile; reads/MFMA/stage in a single
// compiler-scheduled region. 4-chunk XOR swizzle, involution on both sides.
template<int NT, int WN, int GM, int EPI, int KTOT, int NBN, int MINW>
__global__ __launch_bounds__(NT, MINW)
void k_p3(const __hip_bfloat16* __restrict__ A, const __hip_bfloat16* __restrict__ BT,
          const float* __restrict__ b0p, const float* __restrict__ b1p,
          const float* __restrict__ b2p,
          __hip_bfloat16* __restrict__ obf, float* __restrict__ of32,
          const __hip_bfloat16* __restrict__ hres) {
    constexpr int BN = WN * 64;
    constexpr int KT = KTOT / 32;
    constexpr int PER = GM * NBN;
    constexpr int A_LOADS = (128 * 4) / NT;      // 16B loads per thread per A-tile
    constexpr int B_LOADS = (BN * 4) / NT;
    constexpr int LPT = A_LOADS + B_LOADS;       // loads per thread per K-tile
    constexpr int RSWEEP = NT / 4;               // rows covered per load sweep

    __shared__ __hip_bfloat16 AS[3][128 * 32];
    __shared__ __hip_bfloat16 BS[3][BN * 32];

    const int tid = threadIdx.x, wave = tid >> 6, lane = tid & 63;
    const int lo = lane & 15, hi = lane >> 4;
    const int wm = wave / WN, wn = wave % WN;

    // bijective XCD swizzle + group-major (GM bm-rows per group)
    const int nwg = gridDim.x, q = nwg >> 3;
    const int bid = blockIdx.x;
    const int swz = (bid & 7) * q + (bid >> 3);
    const int g = swz / PER, r = swz % PER;
    const int bm = g * GM + (r % GM);
    const int bn = r / GM;
    const size_t m0 = (size_t)bm * 128, n0 = (size_t)bn * BN;

    // staging geometry: per thread row r0 = tid>>2, 16B chunk = (tid&3)^(r0&3)
    const int r0 = tid >> 2;
    const int gcc = (tid & 3) ^ (r0 & 3);
    const __hip_bfloat16* aG = A  + (m0 + r0) * (size_t)KTOT + gcc * 8;
    const __hip_bfloat16* bG = BT + (n0 + r0) * (size_t)KTOT + gcc * 8;

    // fragment read bases: elem = row*32 + (hi^(row&3))*8, row&3 == lo&3
    const int cR = (hi ^ (lo & 3)) * 8;
    const int aOff = (wm * 64 + lo) * 32 + cR;
    const int bOff = (wn * 64 + lo) * 32 + cR;

    floatx4 acc[4][4] = {};

#define STAGE(buf, kt)                                                        \
    do {                                                                      \
        _Pragma("unroll")                                                     \
        for (int s = 0; s < A_LOADS; ++s)                                     \
            gload16(aG + (size_t)(s * RSWEEP) * KTOT + (size_t)(kt) * 32,     \
                    &AS[buf][(s * NT + wave * 64) * 8]);                      \
        _Pragma("unroll")                                                     \
        for (int s = 0; s < B_LOADS; ++s)                                     \
            gload16(bG + (size_t)(s * RSWEEP) * KTOT + (size_t)(kt) * 32,     \
                    &BS[buf][(s * NT + wave * 64) * 8]);                      \
    } while (0)

#define WAITVM_LPT()                                                          \
    do {                                                                      \
        if constexpr (LPT == 3) asm volatile("s_waitcnt vmcnt(3)" ::: "memory"); \
        else                    asm volatile("s_waitcnt vmcnt(4)" ::: "memory"); \
    } while (0)

    // prologue: stage tiles 0 and 1; wait for tile 0 only (tile 1 stays in flight)
    STAGE(0, 0);
    STAGE(1, 1);
    WAITVM_LPT();
    __builtin_amdgcn_sched_barrier(0);
    __builtin_amdgcn_s_barrier();

    int cur = 0, nb = 2;
    for (int t = 0; t < KT; ++t) {
        const int tf = (t + 2 < KT) ? (t + 2) : t;   // tail: dummy re-stage (L2-hot)
        STAGE(nb, tf);

        const __hip_bfloat16* aL = &AS[cur][0];
        const __hip_bfloat16* bL = &BS[cur][0];
        short8 afr[4], bfr[4];
#pragma unroll
        for (int f = 0; f < 4; ++f) afr[f] = *(const short8*)(aL + aOff + f * 512);
#pragma unroll
        for (int f = 0; f < 4; ++f) bfr[f] = *(const short8*)(bL + bOff + f * 512);

        __builtin_amdgcn_s_setprio(1);
#pragma unroll
        for (int mf = 0; mf < 4; ++mf)
#pragma unroll
            for (int nf = 0; nf < 4; ++nf)
                acc[mf][nf] = __builtin_amdgcn_mfma_f32_16x16x32_bf16(
                    afr[mf], bfr[nf], acc[mf][nf], 0, 0, 0);
        __builtin_amdgcn_s_setprio(0);

        WAITVM_LPT();                      // drains tile t+1's loads; t+2's stay in flight
        __builtin_amdgcn_sched_barrier(0);
        __builtin_amdgcn_s_barrier();

        cur = (cur == 2) ? 0 : cur + 1;
        nb  = (nb  == 2) ? 0 : nb  + 1;
    }
#undef STAGE
#undef WAITVM_LPT

    // ---- epilogue ----
#pragma unroll
    for (int mf = 0; mf < 4; ++mf) {
        const int row = (int)m0 + wm * 64 + mf * 16 + hi * 4;
#pragma unroll
        for (int nf = 0; nf < 4; ++nf) {
            const int col = (int)n0 + wn * 64 + nf * 16 + lo;
#pragma unroll
            for (int rr = 0; rr < 4; ++rr) {
                float v = acc[mf][nf][rr];
                const size_t ro = (size_t)(row + rr);
                if (EPI == 0) {
                    float bia = (col < 1024) ? b0p[col]
                              : (col < 2048 ? b1p[col - 1024] : b2p[col - 2048]);
                    obf[ro * NQKV + col] = __float2bfloat16(v + bia);
                } else if (EPI == 1) {
                    v += b0p[col];
                    v = 0.5f * v * (1.0f + erff(v * 0.70710678118654752440f));
                    obf[ro * F_ + col] = __float2bfloat16(v);
                } else {
                    v += b0p[col];
                    v += b2f(*(const unsigned short*)&hres[ro * D_ + col]);
                    of32[ro * D_ + col] = v;
                }
            }
        }
    }
}

// ---------------- sliding-window attention (unchanged, verified) ----------------
__global__ __launch_bounds__(256, 2)
void k_attn(const __hip_bfloat16* __restrict__ qkv, const float* __restrict__ mask,
            const __hip_bfloat16* __restrict__ vtg, __hip_bfloat16* __restrict__ attnb) {
    constexpr int PS = 296;
    __shared__ __hip_bfloat16 P[4][16 * PS];
    const int tid = threadIdx.x, wave = tid >> 6, lane = tid & 63;
    const int bh = blockIdx.y, b = bh >> 4, h = bh & 15;
    const int q0 = blockIdx.x * 64 + wave * 16;
    const int lo = lane & 15, hi = lane >> 4;

    short8 qf0, qf1;
    {
        const __hip_bfloat16* qb = qkv + (size_t)(b * L_ + q0 + lo) * NQKV + h * DH + hi * 8;
        qf0 = *(const short8*)qb;
        qf1 = *(const short8*)(qb + 32);
    }

    floatx4 sc[17];
    const __hip_bfloat16* kcol = qkv + (size_t)b * L_ * NQKV + D_ + h * DH + hi * 8;
#pragma unroll
    for (int t = 0; t < 17; t++) {
        int jg = q0 - 128 + t * 16 + lo;
        int jc = jg < 0 ? 0 : (jg >= L_ ? L_ - 1 : jg);
        const __hip_bfloat16* kb = kcol + (size_t)jc * NQKV;
        short8 kf0 = *(const short8*)kb;
        short8 kf1 = *(const short8*)(kb + 32);
        floatx4 a = {};
        a = __builtin_amdgcn_mfma_f32_16x16x32_bf16(qf0, kf0, a, 0, 0, 0);
        a = __builtin_amdgcn_mfma_f32_16x16x32_bf16(qf1, kf1, a, 0, 0, 0);
        float mval = mask[b * L_ + jc];
        bool jok = (jg >= 0) && (jg < L_) && (mval == 0.0f);
#pragma unroll
        for (int r = 0; r < 4; r++) {
            int qi = q0 + hi * 4 + r;
            bool ok = jok && (jg >= qi - 128) && (jg <= qi + 128);
            a[r] = ok ? a[r] * 0.125f : -1e9f;
        }
        sc[t] = a;
    }

#pragma unroll
    for (int r = 0; r < 4; r++) {
        float m = -3e38f;
#pragma unroll
        for (int t = 0; t < 17; t++) m = fmaxf(m, sc[t][r]);
        m = fmaxf(m, __shfl_xor(m, 1));
        m = fmaxf(m, __shfl_xor(m, 2));
        m = fmaxf(m, __shfl_xor(m, 4));
        m = fmaxf(m, __shfl_xor(m, 8));
        float s = 0.0f;
#pragma unroll
        for (int t = 0; t < 17; t++) { float e = __expf(sc[t][r] - m); sc[t][r] = e; s += e; }
        s += __shfl_xor(s, 1); s += __shfl_xor(s, 2);
        s += __shfl_xor(s, 4); s += __shfl_xor(s, 8);
        float inv = 1.0f / s;
#pragma unroll
        for (int t = 0; t < 17; t++) sc[t][r] *= inv;
    }

    __hip_bfloat16* Pw = &P[wave][0];
#pragma unroll
    for (int t = 0; t < 17; t++)
#pragma unroll
        for (int r = 0; r < 4; r++)
            Pw[(hi * 4 + r) * PS + t * 16 + lo] = __float2bfloat16(sc[t][r]);
    {
        int zr = lane >> 2, zc = 272 + (lane & 3) * 4;
        __hip_bfloat16 z = __float2bfloat16(0.0f);
#pragma unroll
        for (int i = 0; i < 4; i++) Pw[zr * PS + zc + i] = z;
    }

    floatx4 o[4] = {};
#pragma unroll
    for (int st = 0; st < 9; st++) {
        short8 pa = *(const short8*)(Pw + lo * PS + st * 32 + hi * 8);
        int jb = q0 - 128 + st * 32 + hi * 8;
#pragma unroll
        for (int dt = 0; dt < 4; dt++) {
            const __hip_bfloat16* vb = vtg + (long)(bh * DH + dt * 16 + lo) * L_ + jb;
            short8 vf = *(const short8*)vb;
            o[dt] = __builtin_amdgcn_mfma_f32_16x16x32_bf16(pa, vf, o[dt], 0, 0, 0);
        }
    }

#pragma unroll
    for (int dt = 0; dt < 4; dt++)
#pragma unroll
        for (int r = 0; r < 4; r++) {
            int row = q0 + hi * 4 + r;
            attnb[(size_t)(b * L_ + row) * D_ + h * DH + dt * 16 + lo] =
                __float2bfloat16(o[dt][r]);
        }
}

// ---------------- residual + LayerNorm ----------------
__global__ __launch_bounds__(256)
void k_ln(const float* __restrict__ x, const __hip_bfloat16* __restrict__ attnb,
          const float* __restrict__ g, const float* __restrict__ bt,
          __hip_bfloat16* __restrict__ hb) {
    const int row = blockIdx.x, tid = threadIdx.x;
    const int c4 = tid * 4;
    float4 xv = *(const float4*)(x + (size_t)row * D_ + c4);
    short4v av = *(const short4v*)(attnb + (size_t)row * D_ + c4);
    float h0 = xv.x + b2f((unsigned short)av[0]);
    float h1 = xv.y + b2f((unsigned short)av[1]);
    float h2 = xv.z + b2f((unsigned short)av[2]);
    float h3 = xv.w + b2f((unsigned short)av[3]);
    float s = h0 + h1 + h2 + h3;
    float q = h0 * h0 + h1 * h1 + h2 * h2 + h3 * h3;
#pragma unroll
    for (int off = 32; off > 0; off >>= 1) {
        s += __shfl_down(s, off);
        q += __shfl_down(q, off);
    }
    __shared__ float red[8];
    int wave = tid >> 6, lane = tid & 63;
    if (lane == 0) { red[wave] = s; red[4 + wave] = q; }
    __syncthreads();
    s = red[0] + red[1] + red[2] + red[3];
    q = red[4] + red[5] + red[6] + red[7];
    float mu = s * (1.0f / D_);
    float var = q * (1.0f / D_) - mu * mu;
    float inv = rsqrtf(var + 1e-5f);
    float4 gv = *(const float4*)(g + c4);
    float4 bv = *(const float4*)(bt + c4);
    alignas(8) __hip_bfloat16 ov[4];
    ov[0] = __float2bfloat16((h0 - mu) * inv * gv.x + bv.x);
    ov[1] = __float2bfloat16((h1 - mu) * inv * gv.y + bv.y);
    ov[2] = __float2bfloat16((h2 - mu) * inv * gv.z + bv.z);
    ov[3] = __float2bfloat16((h3 - mu) * inv * gv.w + bv.w);
    *(short4v*)(hb + (size_t)row * D_ + c4) = *(const short4v*)ov;
}

// ---------------- launch ----------------
extern "C" void kernel_launch(void* const* d_in, const int* in_sizes, int n_in,
                              void* d_out, int out_size, void* d_ws, size_t ws_size,
                              hipStream_t stream) {
    const float* x    = (const float*)d_in[0];
    const float* mask = (const float*)d_in[1];
    const float* Wq   = (const float*)d_in[2];
    const float* bq   = (const float*)d_in[3];
    const float* Wk   = (const float*)d_in[4];
    const float* bk   = (const float*)d_in[5];
    const float* Wv   = (const float*)d_in[6];
    const float* bv   = (const float*)d_in[7];
    const float* ln_g = (const float*)d_in[8];
    const float* ln_b = (const float*)d_in[9];
    const float* W1   = (const float*)d_in[10];
    const float* b1   = (const float*)d_in[11];
    const float* W2   = (const float*)d_in[12];
    const float* b2   = (const float*)d_in[13];
    float* out = (float*)d_out;
    char* ws = (char*)d_ws;

    __hip_bfloat16* xb   = (__hip_bfloat16*)(ws + OFF_XB);
    __hip_bfloat16* wct  = (__hip_bfloat16*)(ws + OFF_WCT);
    __hip_bfloat16* w1t  = (__hip_bfloat16*)(ws + OFF_W1T);
    __hip_bfloat16* w2t  = (__hip_bfloat16*)(ws + OFF_W2T);
    __hip_bfloat16* qkvb = (__hip_bfloat16*)(ws + OFF_QKV);
    __hip_bfloat16* vtg  = (__hip_bfloat16*)(ws + OFF_VT) + VT_GUARD;
    __hip_bfloat16* attb = (__hip_bfloat16*)(ws + OFF_ATT);
    __hip_bfloat16* hb   = (__hip_bfloat16*)(ws + OFF_HB);
    __hip_bfloat16* midb = (__hip_bfloat16*)(ws + OFF_MID);

    // input conversions
    k_cvt_x<<<(M_ * D_) / 2048, 256, 0, stream>>>(x, xb);
    k_tcvt<<<dim3(D_ / 64, D_ / 64), 256, 0, stream>>>(Wq, wct,                   D_, D_);
    k_tcvt<<<dim3(D_ / 64, D_ / 64), 256, 0, stream>>>(Wk, wct + 1024 * 1024,     D_, D_);
    k_tcvt<<<dim3(D_ / 64, D_ / 64), 256, 0, stream>>>(Wv, wct + 2 * 1024 * 1024, D_, D_);
    k_tcvt<<<dim3(F_ / 64, D_ / 64), 256, 0, stream>>>(W1, w1t, D_, F_);
    k_tcvt<<<dim3(D_ / 64, F_ / 64), 256, 0, stream>>>(W2, w2t, F_, D_);

    // fused QKV projection: BM=128, BN=256 -> grid 64*12 = 768
    k_p3<512, 4, 8, 0, D_, 12, 4><<<768, 512, 0, stream>>>(
        xb, wct, bq, bk, bv, qkvb, nullptr, nullptr);

    // V transpose, attention
    k_vtrans<<<dim3(L_ / 64, B_ * H_), 256, 0, stream>>>(qkvb, vtg);
    k_attn<<<dim3(L_ / 64, B_ * H_), 256, 0, stream>>>(qkvb, mask, vtg, attb);

    // residual + LN
    k_ln<<<M_, 256, 0, stream>>>(x, attb, ln_g, ln_b, hb);

    // FFN1: BM=128, BN=256 -> grid 64*16 = 1024
    k_p3<512, 4, 8, 1, D_, 16, 4><<<1024, 512, 0, stream>>>(
        hb, w1t, b1, nullptr, nullptr, midb, nullptr, nullptr);
    // FFN2: BM=128, BN=128 -> grid 64*8 = 512 (3 blocks/CU-capable, 2 resident)
    k_p3<256, 2, 2, 2, F_, 8, 3><<<512, 256, 0, stream>>>(
        midb, w2t, b2, nullptr, nullptr, nullptr, out, hb);
}